// Round 5
// baseline (695.530 us; speedup 1.0000x reference)
//
#include <hip/hip_runtime.h>
#include <hip/hip_bf16.h>
#include <hip/hip_cooperative_groups.h>

namespace cg = cooperative_groups;

// Round 15: ONE cooperative mega-kernel (7 grid.sync-separated phases:
// zero | bin+cvt | build | agg1 | gemm1 | agg2 | gemm2). Rationale: R0-R4
// arithmetic shows each separate dispatch carries ~6-8us of fixed overhead
// (gemm measures 42-47us vs a ~5us first-principles cost; MODE1==MODE2 rules
// out the epilogue) -- ~40us of the 210us budget is dispatch tax. All phases
// grid-stride over virtual blocks so the gather keeps ~50K independent waves
// (R14's fused-tile serialization avoided). LDS shrunk to exactly 32768 B
// (Wl: stride-128 + 16B-unit XOR swizzle; Tl: stride-128 + col rotation) ->
// 5 blocks/CU = 20 waves/CU for the gather phase. Fallback: 6-kernel path
// with the same device bodies if cooperative launch fails.
// Gather = R10's proven agg_q (row-major 128-B fp8 rows, 16-B lane loads).
// Dropout: JAX partitionable threefry (verified R2). absmax budget ~0.08.

#define HDIM 128
#define KDIM 256
#define NBUK 256
#define BNODE 196   // nodes per bucket (256*196 = 50176 >= 50000)
#define BCAP 4096   // edge capacity per bucket (mean 3136, sigma ~56)
#define BCH 2048    // edges per WG in bin

typedef __attribute__((ext_vector_type(8))) short bshort8;
typedef __attribute__((ext_vector_type(4))) float f32x4;
typedef __attribute__((ext_vector_type(2))) float f32x2;

struct MegaArgs {
  const int* src; const int* dst;
  int* bucketCount; unsigned int* pairs;
  int* deg; int* rowptr; ushort* eidx;
  const float* x;
  const float* Wl0; const float* bl0; const float* Wr0;
  const float* Wl1; const float* bl1; const float* Wr1;
  ushort* Xb; ushort* Hb; ushort* Ag;
  unsigned char* Xq; unsigned char* Hq;
  ushort* Wc0; ushort* Wc1;
  float* out;
  int E, EB, CB, GB, AB, N;
};

__device__ __forceinline__ ushort f2b(float f) {
  __hip_bfloat16 h = __float2bfloat16(f);  // RTNE
  return *(ushort*)&h;
}
__device__ __forceinline__ unsigned int pack2(float lo, float hi) {
  return (unsigned int)f2b(lo) | ((unsigned int)f2b(hi) << 16);
}

// ---------------- fp8 e4m3 codec (HW builtins if present, manual fallback) ----
#if __has_builtin(__builtin_amdgcn_cvt_pk_f32_fp8) && __has_builtin(__builtin_amdgcn_cvt_pk_fp8_f32)
#define FP8_HW 1
#endif

__device__ __forceinline__ unsigned int fp8e1(float f) {  // manual e4m3fn RTNE
  unsigned int u = __float_as_uint(f);
  unsigned int s = (u >> 24) & 0x80u;
  unsigned int mag = u & 0x7FFFFFFFu;
  if (mag < 0x38800000u) return s;           // flush |f|<2^-6 to zero
  if (mag > 0x43E00000u) mag = 0x43E00000u;  // clamp to 448
  unsigned int r = mag + 0x7FFFFu + ((mag >> 20) & 1u);
  return s | ((r >> 20) - 960u);
}
__device__ __forceinline__ float fp8d1(unsigned int b) {
  unsigned int v = b & 0x7Fu;
  float fn = __uint_as_float(((b & 0x80u) << 24) | ((v + 960u) << 20));
  return v >= 8u ? fn : 0.0f;
}

__device__ __forceinline__ unsigned int fp8x4_enc(float f0, float f1, float f2, float f3) {
#ifdef FP8_HW
  int u = 0;
  u = __builtin_amdgcn_cvt_pk_fp8_f32(f0, f1, u, false);
  u = __builtin_amdgcn_cvt_pk_fp8_f32(f2, f3, u, true);
  return (unsigned int)u;
#else
  return fp8e1(f0) | (fp8e1(f1) << 8) | (fp8e1(f2) << 16) | (fp8e1(f3) << 24);
#endif
}
__device__ __forceinline__ void fp8x4_acc(float* a, unsigned int w) {
#ifdef FP8_HW
  f32x2 lo = __builtin_amdgcn_cvt_pk_f32_fp8((int)w, false);
  f32x2 hi = __builtin_amdgcn_cvt_pk_f32_fp8((int)w, true);
  a[0] += lo.x; a[1] += lo.y; a[2] += hi.x; a[3] += hi.y;
#else
  a[0] += fp8d1(w & 255u); a[1] += fp8d1((w >> 8) & 255u);
  a[2] += fp8d1((w >> 16) & 255u); a[3] += fp8d1(w >> 24);
#endif
}

// ---------------- Threefry-2x32 (JAX partitionable mode, verified R2) --------
__device__ __forceinline__ unsigned int tf_rotl(unsigned int x, int d) {
  return (x << d) | (x >> (32 - d));
}
__device__ __forceinline__ bool dropout_keep(unsigned int j) {
  unsigned int x0 = 0u, x1 = j;
  const unsigned int ks0 = 0u, ks1 = 42u, ks2 = 0x1BD11BDAu ^ 0u ^ 42u;
  x0 += ks0; x1 += ks1;
#define TF_R(r) { x0 += x1; x1 = tf_rotl(x1, (r)); x1 ^= x0; }
  TF_R(13) TF_R(15) TF_R(26) TF_R(6)
  x0 += ks1; x1 += ks2 + 1u;
  TF_R(17) TF_R(29) TF_R(16) TF_R(24)
  x0 += ks2; x1 += ks0 + 2u;
  TF_R(13) TF_R(15) TF_R(26) TF_R(6)
  x0 += ks0; x1 += ks1 + 3u;
  TF_R(17) TF_R(29) TF_R(16) TF_R(24)
  x0 += ks1; x1 += ks2 + 4u;
  TF_R(13) TF_R(15) TF_R(26) TF_R(6)
  x0 += ks2; x1 += ks0 + 5u;
#undef TF_R
  unsigned int r = x0 ^ x1;
  float u = __uint_as_float((r >> 9) | 0x3f800000u) - 1.0f;
  return u < 0.5f;
}

// ======================= device bodies (shared by mega + fallback) ==========

__device__ __forceinline__ void bin_cvt_body(const MegaArgs& A, int b, char* smem) {
  int* hist = (int*)smem;
  int* lofs = hist + NBUK;
  int* lcur = lofs + NBUK;
  int* gbase = lcur + NBUK;
  unsigned int* ordv = (unsigned int*)(gbase + NBUK);
  unsigned char* ordb = (unsigned char*)(ordv + BCH);

  if (b >= A.EB) {
    b -= A.EB;
    if (b < 64) {  // weights -> combined bf16 [Wl | Wr] rows of 256
      int t = b * 256 + threadIdx.x;  // 16384
      int o = t >> 7, k = t & 127;
      A.Wc0[o * KDIM + k] = f2b(A.Wl0[t]);
      A.Wc0[o * KDIM + HDIM + k] = f2b(A.Wr0[t]);
      A.Wc1[o * KDIM + k] = f2b(A.Wl1[t]);
      A.Wc1[o * KDIM + HDIM + k] = f2b(A.Wr1[t]);
    } else {       // x -> bf16 + fp8
      int t = (b - 64) * 256 + threadIdx.x;
      if (t < A.N * 32) {
        int n = t >> 5, c4 = t & 31;
        float4 v = *(const float4*)&A.x[(size_t)n * HDIM + c4 * 4];
        uint2 p;
        p.x = pack2(v.x, v.y);
        p.y = pack2(v.z, v.w);
        *(uint2*)&A.Xb[(size_t)n * HDIM + c4 * 4] = p;
        *(unsigned int*)&A.Xq[(size_t)n * HDIM + c4 * 4] = fp8x4_enc(v.x, v.y, v.z, v.w);
      }
    }
    return;
  }

  // ---- bin work ----
  hist[threadIdx.x] = 0;
  __syncthreads();
  int begin = b * BCH;
  int n = min(BCH, A.E - begin);
  unsigned int vals[BCH / 256];
  int bks[BCH / 256];
  int cnt = 0;
  for (int i = threadIdx.x; i < n; i += 256) {
    int s = A.src[begin + i], d = A.dst[begin + i];
    int bk = d / BNODE;
    int dloc = d - bk * BNODE;
    vals[cnt] = ((unsigned int)s << 8) | (unsigned int)dloc;
    bks[cnt] = bk;
    ++cnt;
    atomicAdd(&hist[bk], 1);
  }
  __syncthreads();
  {
    int v = hist[threadIdx.x];
    lofs[threadIdx.x] = v;
    __syncthreads();
    for (int off = 1; off < NBUK; off <<= 1) {
      int t = (threadIdx.x >= off) ? lofs[threadIdx.x - off] : 0;
      __syncthreads();
      lofs[threadIdx.x] += t;
      __syncthreads();
    }
    int ex = lofs[threadIdx.x] - v;
    __syncthreads();
    lofs[threadIdx.x] = ex;
    lcur[threadIdx.x] = ex;
    gbase[threadIdx.x] = atomicAdd(&A.bucketCount[threadIdx.x], v);
  }
  __syncthreads();
  for (int k = 0; k < cnt; ++k) {
    int bk = bks[k];
    int p = atomicAdd(&lcur[bk], 1);
    ordv[p] = vals[k];
    ordb[p] = (unsigned char)bk;
  }
  __syncthreads();
  for (int j = threadIdx.x; j < n; j += 256) {
    int bk = ordb[j];
    A.pairs[bk * BCAP + gbase[bk] + (j - lofs[bk])] = ordv[j];
  }
}

__device__ __forceinline__ void build_body(const MegaArgs& A, int b, char* smem) {
  int* h = (int*)smem;
  int* lofs = h + BNODE;
  int* cur = lofs + BNODE;
  const int base = b * BCAP;
  const int cnt = A.bucketCount[b];
  const int nodebase = b * BNODE;
  const int nloc = min(BNODE, A.N - nodebase);
  if (threadIdx.x < BNODE) h[threadIdx.x] = 0;
  __syncthreads();
  for (int i = threadIdx.x; i < cnt; i += 256) atomicAdd(&h[A.pairs[base + i] & 255u], 1);
  __syncthreads();
  if (threadIdx.x < BNODE) lofs[threadIdx.x] = h[threadIdx.x];
  __syncthreads();
  for (int off = 1; off < BNODE; off <<= 1) {
    int t = (threadIdx.x >= off && threadIdx.x < BNODE) ? lofs[threadIdx.x - off] : 0;
    __syncthreads();
    if (threadIdx.x < BNODE) lofs[threadIdx.x] += t;
    __syncthreads();
  }
  if (threadIdx.x < BNODE) {
    int ex = lofs[threadIdx.x] - h[threadIdx.x];
    cur[threadIdx.x] = ex;
    if (threadIdx.x < nloc) {
      A.deg[nodebase + threadIdx.x] = h[threadIdx.x];
      A.rowptr[nodebase + threadIdx.x] = base + ex;
    }
  }
  __syncthreads();
  for (int i = threadIdx.x; i < cnt; i += 256) {
    unsigned int v = A.pairs[base + i];
    int pos = atomicAdd(&cur[v & 255u], 1);
    A.eidx[base + pos] = (ushort)(v >> 8);
  }
}

// R10's proven agg_q: one wave per node, 128-B fp8 rows, 16-B lane loads,
// unroll 2 -> 16 edges in flight. No LDS, no early return (mega-safe).
__device__ __forceinline__ void agg_body(const unsigned char* __restrict__ Fq,
                                         ushort* __restrict__ Ag,
                                         const ushort* __restrict__ eidx,
                                         const int* __restrict__ rowptr,
                                         const int* __restrict__ deg, int N, int vb) {
  const int lane = threadIdx.x & 63;
  const int n = vb * 4 + (threadIdx.x >> 6);
  if (n >= N) return;  // per-wave uniform; safe inside phase loop
  const int start = rowptr[n];
  const int d = deg[n];
  const int es = lane >> 3;
  const int cl = lane & 7;
  float a[16];
#pragma unroll
  for (int i = 0; i < 16; ++i) a[i] = 0.0f;
  for (int j = 0; j < d; j += 16) {
    uint4 v[2];
    bool m[2];
#pragma unroll
    for (int u = 0; u < 2; ++u) {
      int e = j + u * 8 + es;
      m[u] = e < d;
      if (m[u]) {
        int s = eidx[start + e];
        v[u] = *(const uint4*)&Fq[(size_t)s * HDIM + cl * 16];
      }
    }
#pragma unroll
    for (int u = 0; u < 2; ++u)
      if (m[u]) {
        fp8x4_acc(&a[0], v[u].x);
        fp8x4_acc(&a[4], v[u].y);
        fp8x4_acc(&a[8], v[u].z);
        fp8x4_acc(&a[12], v[u].w);
      }
  }
#pragma unroll
  for (int i = 0; i < 16; ++i) {
    a[i] += __shfl_xor(a[i], 8, 64);
    a[i] += __shfl_xor(a[i], 16, 64);
    a[i] += __shfl_xor(a[i], 32, 64);
  }
  if (es == 0) {
    float rd = 1.0f / fmaxf((float)d, 1.0f);
    uint4 p0, p1;
    p0.x = pack2(a[0] * rd, a[1] * rd);
    p0.y = pack2(a[2] * rd, a[3] * rd);
    p0.z = pack2(a[4] * rd, a[5] * rd);
    p0.w = pack2(a[6] * rd, a[7] * rd);
    p1.x = pack2(a[8] * rd, a[9] * rd);
    p1.y = pack2(a[10] * rd, a[11] * rd);
    p1.z = pack2(a[12] * rd, a[13] * rd);
    p1.w = pack2(a[14] * rd, a[15] * rd);
    *(uint4*)&Ag[(size_t)n * HDIM + cl * 16] = p0;
    *(uint4*)&Ag[(size_t)n * HDIM + cl * 16 + 8] = p1;
  }
}

// K=256 bf16 MFMA GEMM tile (64 nodes). LDS = 32768 B exactly:
//   Wl: 128 rows x 128 ushorts, 16B-unit XOR swizzle u^=(row&15)  (26KB.. 32KB)
//   Tl: 4 waves x 16 rows x 128 f32, col rotation (col+4*row)&127
// mode 1: relu+dropout -> Hb (bf16) + Hq (fp8). mode 2: f32 out.
__device__ __forceinline__ void gemm_body(const MegaArgs& A, int vb, int mode, char* smem) {
  ushort* Wl = (ushort*)smem;
  float* Tl = (float*)smem;
  const ushort* Agg = A.Ag;
  const ushort* F = (mode == 1) ? A.Xb : A.Hb;
  const ushort* Wc = (mode == 1) ? A.Wc0 : A.Wc1;
  const float* bias = (mode == 1) ? A.bl0 : A.bl1;
  const int N = A.N;
  const int tid = threadIdx.x;
  const int lane = tid & 63;
  const int wid = tid >> 6;
  const int quad = lane >> 4;
  const int l15 = lane & 15;
  const int n0 = vb * 64;

  int rowA = n0 + wid * 16 + l15;
  if (rowA >= N) rowA = N - 1;
  bshort8 afA[4], afF[4];
#pragma unroll
  for (int ks = 0; ks < 4; ++ks) {
    afA[ks] = *(const bshort8*)&Agg[(size_t)rowA * HDIM + ks * 32 + quad * 8];
    afF[ks] = *(const bshort8*)&F[(size_t)rowA * HDIM + ks * 32 + quad * 8];
  }

  f32x4 acc[8];
#pragma unroll
  for (int i = 0; i < 8; ++i) acc[i] = (f32x4){0.f, 0.f, 0.f, 0.f};

#pragma unroll
  for (int half = 0; half < 2; ++half) {
    __syncthreads();
#pragma unroll
    for (int i = 0; i < 8; ++i) {
      int q = i * 256 + tid;
      int row = q >> 4, u = q & 15;
      *(uint4*)&Wl[row * 128 + ((u ^ (row & 15)) << 3)] =
          *(const uint4*)&Wc[row * KDIM + half * HDIM + u * 8];
    }
    __syncthreads();
#pragma unroll
    for (int ks = 0; ks < 4; ++ks) {
#pragma unroll
      for (int os = 0; os < 8; ++os) {
        // row = os*16 + l15 -> row&15 == l15
        bshort8 bf = *(const bshort8*)&Wl[(os * 16 + l15) * 128 + (((ks * 4 + quad) ^ l15) << 3)];
        acc[os] = __builtin_amdgcn_mfma_f32_16x16x32_bf16(
            half == 0 ? afA[ks] : afF[ks], bf, acc[os], 0, 0, 0);
      }
    }
  }

  __syncthreads();  // done with Wl; reuse as transpose buffer

  const int wbase = wid * (16 * 128);
#pragma unroll
  for (int os = 0; os < 8; ++os)
#pragma unroll
    for (int r = 0; r < 4; ++r) {
      int row = quad * 4 + r;
      Tl[wbase + row * 128 + ((os * 16 + l15 + 4 * row) & 127)] = acc[os][r];
    }

  __syncthreads();

#pragma unroll
  for (int i = 0; i < 8; ++i) {
    int q = i * 64 + lane;
    int r = q >> 5;
    int c4 = q & 31;
    int n = n0 + wid * 16 + r;
    if (n >= N) continue;
    int c = c4 * 4;
    float4 v = *(float4*)&Tl[wbase + r * 128 + ((c + 4 * r) & 127)];
    const float4 bv = *(const float4*)&bias[c];
    v.x += bv.x; v.y += bv.y; v.z += bv.z; v.w += bv.w;
    if (mode == 1) {
      v.x = v.x > 0.0f ? v.x : 0.0f;
      v.y = v.y > 0.0f ? v.y : 0.0f;
      v.z = v.z > 0.0f ? v.z : 0.0f;
      v.w = v.w > 0.0f ? v.w : 0.0f;
      unsigned int fj = (unsigned int)n * HDIM + (unsigned int)c;
      v.x = dropout_keep(fj + 0u) ? v.x * 2.0f : 0.0f;
      v.y = dropout_keep(fj + 1u) ? v.y * 2.0f : 0.0f;
      v.z = dropout_keep(fj + 2u) ? v.z * 2.0f : 0.0f;
      v.w = dropout_keep(fj + 3u) ? v.w * 2.0f : 0.0f;
      uint2 p;
      p.x = pack2(v.x, v.y);
      p.y = pack2(v.z, v.w);
      *(uint2*)&A.Hb[(size_t)n * HDIM + c] = p;
      *(unsigned int*)&A.Hq[(size_t)n * HDIM + c] = fp8x4_enc(v.x, v.y, v.z, v.w);
    } else {
      *(float4*)&A.out[(size_t)n * HDIM + c] = v;
    }
  }
}

// ======================= mega kernel (cooperative) ==========================
__global__ __launch_bounds__(256, 5) void mega_k(MegaArgs A) {
  cg::grid_group grid = cg::this_grid();
  __shared__ char smem[32768];
  const int gb = gridDim.x;

  // P0: zero bucketCount
  if (blockIdx.x == 0 && threadIdx.x < NBUK) A.bucketCount[threadIdx.x] = 0;
  grid.sync();
  // P1: bin + cvt
  for (int vb = blockIdx.x; vb < A.CB; vb += gb) { bin_cvt_body(A, vb, smem); __syncthreads(); }
  grid.sync();
  // P2: build CSR
  for (int vb = blockIdx.x; vb < NBUK; vb += gb) { build_body(A, vb, smem); __syncthreads(); }
  grid.sync();
  // P3: agg layer 1
  for (int vb = blockIdx.x; vb < A.AB; vb += gb)
    agg_body(A.Xq, A.Ag, A.eidx, A.rowptr, A.deg, A.N, vb);
  grid.sync();
  // P4: gemm layer 1
  for (int vb = blockIdx.x; vb < A.GB; vb += gb) { gemm_body(A, vb, 1, smem); __syncthreads(); }
  grid.sync();
  // P5: agg layer 2
  for (int vb = blockIdx.x; vb < A.AB; vb += gb)
    agg_body(A.Hq, A.Ag, A.eidx, A.rowptr, A.deg, A.N, vb);
  grid.sync();
  // P6: gemm layer 2
  for (int vb = blockIdx.x; vb < A.GB; vb += gb) { gemm_body(A, vb, 2, smem); __syncthreads(); }
}

// ======================= fallback wrappers (non-cooperative path) ===========
__global__ __launch_bounds__(256) void w_bin(MegaArgs A) {
  __shared__ char s[16384];
  bin_cvt_body(A, blockIdx.x, s);
}
__global__ __launch_bounds__(256) void w_build(MegaArgs A) {
  __shared__ char s[2368];
  build_body(A, blockIdx.x, s);
}
__global__ __launch_bounds__(256) void w_agg(MegaArgs A, int layer) {
  agg_body(layer == 1 ? A.Xq : A.Hq, A.Ag, A.eidx, A.rowptr, A.deg, A.N, blockIdx.x);
}
__global__ __launch_bounds__(256) void w_gemm(MegaArgs A, int mode) {
  __shared__ char s[32768];
  gemm_body(A, blockIdx.x, mode, s);
}

extern "C" void kernel_launch(void* const* d_in, const int* in_sizes, int n_in,
                              void* d_out, int out_size, void* d_ws, size_t ws_size,
                              hipStream_t stream) {
  const int N = in_sizes[0] / HDIM;  // 50000
  const int E = in_sizes[1] / 2;     // 800000

  MegaArgs A;
  A.x   = (const float*)d_in[0];
  const int* ei = (const int*)d_in[1];
  A.Wl0 = (const float*)d_in[2];
  A.bl0 = (const float*)d_in[3];
  A.Wr0 = (const float*)d_in[4];
  A.Wl1 = (const float*)d_in[5];
  A.bl1 = (const float*)d_in[6];
  A.Wr1 = (const float*)d_in[7];
  A.out = (float*)d_out;
  A.src = ei;
  A.dst = ei + E;
  A.E = E;
  A.N = N;

  // workspace: bucketCount | deg | rowptr | pairs | eidx | Wc0 | Wc1 |
  //            Xb | Hb | Ag (bf16) | Xq | Hq (fp8)
  const int Na = (N + 63) & ~63;
  A.bucketCount = (int*)d_ws;
  A.deg         = A.bucketCount + NBUK;
  A.rowptr      = A.deg + Na;
  A.pairs       = (unsigned int*)(A.rowptr + Na);
  A.eidx        = (ushort*)(A.pairs + NBUK * BCAP);
  size_t off = (((size_t)(A.eidx + NBUK * BCAP) - (size_t)d_ws) + 255) & ~(size_t)255;
  A.Wc0 = (ushort*)((char*)d_ws + off);
  A.Wc1 = A.Wc0 + 128 * KDIM;
  A.Xb  = A.Wc1 + 128 * KDIM;
  A.Hb  = A.Xb + (size_t)N * HDIM;
  A.Ag  = A.Hb + (size_t)N * HDIM;
  A.Xq  = (unsigned char*)(A.Ag + (size_t)N * HDIM);
  A.Hq  = A.Xq + (size_t)N * HDIM;

  A.EB = (E + BCH - 1) / BCH;                 // 391
  A.GB = (N + 63) / 64;                       // 782
  A.AB = (N + 3) / 4;                         // 12500
  A.CB = A.EB + 64 + (N * 32 + 255) / 256;    // bin + weights + x-cvt

  static int grid_blocks = 0;
  if (grid_blocks == 0) {
    int dev = 0;
    hipGetDevice(&dev);
    int nb = 0;
    hipOccupancyMaxActiveBlocksPerMultiprocessor(&nb, mega_k, 256, 0);
    if (nb < 1) nb = 1;
    int cus = 0;
    hipDeviceGetAttribute(&cus, hipDeviceAttributeMultiprocessorCount, dev);
    if (cus < 1) cus = 256;
    grid_blocks = nb * cus;
  }

  void* kargs[1] = {(void*)&A};
  hipError_t err = hipLaunchCooperativeKernel((const void*)mega_k, dim3(grid_blocks),
                                              dim3(256), kargs, 0, stream);
  if (err != hipSuccess) {
    (void)hipGetLastError();  // clear sticky error; use classic 6-kernel path
    hipMemsetAsync(A.bucketCount, 0, NBUK * sizeof(int), stream);
    w_bin<<<A.CB, 256, 0, stream>>>(A);
    w_build<<<NBUK, 256, 0, stream>>>(A);
    w_agg<<<A.AB, 256, 0, stream>>>(A, 1);
    w_gemm<<<A.GB, 256, 0, stream>>>(A, 1);
    w_agg<<<A.AB, 256, 0, stream>>>(A, 2);
    w_gemm<<<A.GB, 256, 0, stream>>>(A, 2);
  }
}

// Round 6
// 218.140 us; speedup vs baseline: 3.1884x; 3.1884x over previous
//
#include <hip/hip_runtime.h>
#include <hip/hip_bf16.h>

// Round 16: R10 structure restored exactly (best proven: 207.9/210.6 us),
// with ONE change: agg_c replaces agg_q. Reduction-axis reassignment:
// lane L owns output columns 2L,2L+1; the edge loop is wave-uniform
// (scalar eidx/rowptr/deg via readfirstlane). Per edge: 1 coalesced 2-B
// lane load (same two 64-B lines as before), 1 cvt_pk_f32_fp8, 2 adds.
// Eliminates agg_q's 48 __shfl_xor (ds_bpermute, shared LDS pipe) per node,
// all per-lane masks, and the divergent epilogue. R11/R13 showed agg time
// scales with instruction count, not bytes -> issue-bound; this is the
// minimum-instruction form. 4 accumulator pairs (unroll 4) break the
// f32 add dependence chain.
//   bin_cvt_k: blocks [0,EB) bucket edges; [EB,EB+64) weights->bf16;
//              rest: x -> bf16 (Xb) + fp8 (Xq).               (proven R7-R10)
//   build_k:   per-bucket CSR (deg/rowptr/eidx u16).          (proven R7-R10)
//   agg_c:     column-per-lane fp8 gather, f32 acc, bf16 out. (NEW)
//   gemm_mfma: K=256 bf16 16x16x32 MFMA; MODE1 epilogue -> Hb + Hq. (proven)
// Dropout: JAX partitionable threefry (verified R2). absmax budget ~0.08.

#define HDIM 128
#define KDIM 256
#define NBUK 256
#define BNODE 196   // nodes per bucket (256*196 = 50176 >= 50000)
#define BCAP 4096   // edge capacity per bucket (mean 3136, sigma ~56)
#define BCH 2048    // edges per WG in bin

typedef __attribute__((ext_vector_type(8))) short bshort8;
typedef __attribute__((ext_vector_type(4))) float f32x4;
typedef __attribute__((ext_vector_type(2))) float f32x2;

__device__ __forceinline__ ushort f2b(float f) {
  __hip_bfloat16 h = __float2bfloat16(f);  // RTNE
  return *(ushort*)&h;
}
__device__ __forceinline__ unsigned int pack2(float lo, float hi) {
  return (unsigned int)f2b(lo) | ((unsigned int)f2b(hi) << 16);
}

// ---------------- fp8 e4m3 codec (HW builtins if present, manual fallback) ----
#if __has_builtin(__builtin_amdgcn_cvt_pk_f32_fp8) && __has_builtin(__builtin_amdgcn_cvt_pk_fp8_f32)
#define FP8_HW 1
#endif

__device__ __forceinline__ unsigned int fp8e1(float f) {  // manual e4m3fn RTNE
  unsigned int u = __float_as_uint(f);
  unsigned int s = (u >> 24) & 0x80u;
  unsigned int mag = u & 0x7FFFFFFFu;
  if (mag < 0x38800000u) return s;           // flush |f|<2^-6 to zero
  if (mag > 0x43E00000u) mag = 0x43E00000u;  // clamp to 448
  unsigned int r = mag + 0x7FFFFu + ((mag >> 20) & 1u);
  return s | ((r >> 20) - 960u);
}
__device__ __forceinline__ float fp8d1(unsigned int b) {
  unsigned int v = b & 0x7Fu;
  float fn = __uint_as_float(((b & 0x80u) << 24) | ((v + 960u) << 20));
  return v >= 8u ? fn : 0.0f;  // encoder flushes; only v==0 occurs below 8
}

__device__ __forceinline__ unsigned int fp8x4_enc(float f0, float f1, float f2, float f3) {
#ifdef FP8_HW
  int u = 0;
  u = __builtin_amdgcn_cvt_pk_fp8_f32(f0, f1, u, false);
  u = __builtin_amdgcn_cvt_pk_fp8_f32(f2, f3, u, true);
  return (unsigned int)u;
#else
  return fp8e1(f0) | (fp8e1(f1) << 8) | (fp8e1(f2) << 16) | (fp8e1(f3) << 24);
#endif
}

// decode 2 fp8 (low 16 bits of w) and accumulate into a0,a1
__device__ __forceinline__ void fp8x2_acc(float& a0, float& a1, unsigned int w) {
#ifdef FP8_HW
  f32x2 lo = __builtin_amdgcn_cvt_pk_f32_fp8((int)w, false);
  a0 += lo.x; a1 += lo.y;
#else
  a0 += fp8d1(w & 255u); a1 += fp8d1((w >> 8) & 255u);
#endif
}

// ---------------- Threefry-2x32 (JAX partitionable mode, verified R2) --------
__device__ __forceinline__ unsigned int tf_rotl(unsigned int x, int d) {
  return (x << d) | (x >> (32 - d));
}
__device__ __forceinline__ bool dropout_keep(unsigned int j) {
  unsigned int x0 = 0u, x1 = j;
  const unsigned int ks0 = 0u, ks1 = 42u, ks2 = 0x1BD11BDAu ^ 0u ^ 42u;
  x0 += ks0; x1 += ks1;
#define TF_R(r) { x0 += x1; x1 = tf_rotl(x1, (r)); x1 ^= x0; }
  TF_R(13) TF_R(15) TF_R(26) TF_R(6)
  x0 += ks1; x1 += ks2 + 1u;
  TF_R(17) TF_R(29) TF_R(16) TF_R(24)
  x0 += ks2; x1 += ks0 + 2u;
  TF_R(13) TF_R(15) TF_R(26) TF_R(6)
  x0 += ks0; x1 += ks1 + 3u;
  TF_R(17) TF_R(29) TF_R(16) TF_R(24)
  x0 += ks1; x1 += ks2 + 4u;
  TF_R(13) TF_R(15) TF_R(26) TF_R(6)
  x0 += ks2; x1 += ks0 + 5u;
#undef TF_R
  unsigned int r = x0 ^ x1;
  float u = __uint_as_float((r >> 9) | 0x3f800000u) - 1.0f;
  return u < 0.5f;
}

// ---------------- bin (bucket edges) + cvt (weights, x) merged ----------------
__global__ __launch_bounds__(256) void bin_cvt_k(
    const int* __restrict__ src, const int* __restrict__ dst,
    int* __restrict__ bucketCount, unsigned int* __restrict__ pairs, int E, int EB,
    const float* __restrict__ x,
    const float* __restrict__ Wl0, const float* __restrict__ Wr0,
    const float* __restrict__ Wl1, const float* __restrict__ Wr1,
    ushort* __restrict__ Xb, unsigned char* __restrict__ Xq,
    ushort* __restrict__ Wc0, ushort* __restrict__ Wc1, int N) {
  __shared__ int hist[NBUK];
  __shared__ int lofs[NBUK];
  __shared__ int lcur[NBUK];
  __shared__ int gbase[NBUK];
  __shared__ unsigned int ordv[BCH];
  __shared__ unsigned char ordb[BCH];

  int b = blockIdx.x;
  if (b >= EB) {
    b -= EB;
    if (b < 64) {  // weights -> combined bf16 [Wl | Wr] rows of 256
      int t = b * 256 + threadIdx.x;  // 16384
      int o = t >> 7, k = t & 127;
      Wc0[o * KDIM + k] = f2b(Wl0[t]);
      Wc0[o * KDIM + HDIM + k] = f2b(Wr0[t]);
      Wc1[o * KDIM + k] = f2b(Wl1[t]);
      Wc1[o * KDIM + HDIM + k] = f2b(Wr1[t]);
    } else {       // x -> bf16 + fp8
      int t = (b - 64) * 256 + threadIdx.x;
      if (t < N * 32) {
        int n = t >> 5, c4 = t & 31;
        float4 v = *(const float4*)&x[(size_t)n * HDIM + c4 * 4];
        uint2 p;
        p.x = pack2(v.x, v.y);
        p.y = pack2(v.z, v.w);
        *(uint2*)&Xb[(size_t)n * HDIM + c4 * 4] = p;
        *(unsigned int*)&Xq[(size_t)n * HDIM + c4 * 4] = fp8x4_enc(v.x, v.y, v.z, v.w);
      }
    }
    return;
  }

  // ---- bin work ----
  hist[threadIdx.x] = 0;
  __syncthreads();
  int begin = b * BCH;
  int n = min(BCH, E - begin);
  unsigned int vals[BCH / 256];
  int bks[BCH / 256];
  int cnt = 0;
  for (int i = threadIdx.x; i < n; i += 256) {
    int s = src[begin + i], d = dst[begin + i];
    int bk = d / BNODE;
    int dloc = d - bk * BNODE;
    vals[cnt] = ((unsigned int)s << 8) | (unsigned int)dloc;
    bks[cnt] = bk;
    ++cnt;
    atomicAdd(&hist[bk], 1);
  }
  __syncthreads();
  {
    int v = hist[threadIdx.x];
    lofs[threadIdx.x] = v;
    __syncthreads();
    for (int off = 1; off < NBUK; off <<= 1) {
      int t = (threadIdx.x >= off) ? lofs[threadIdx.x - off] : 0;
      __syncthreads();
      lofs[threadIdx.x] += t;
      __syncthreads();
    }
    int ex = lofs[threadIdx.x] - v;
    __syncthreads();
    lofs[threadIdx.x] = ex;
    lcur[threadIdx.x] = ex;
    gbase[threadIdx.x] = atomicAdd(&bucketCount[threadIdx.x], v);
  }
  __syncthreads();
  for (int k = 0; k < cnt; ++k) {
    int bk = bks[k];
    int p = atomicAdd(&lcur[bk], 1);
    ordv[p] = vals[k];
    ordb[p] = (unsigned char)bk;
  }
  __syncthreads();
  for (int j = threadIdx.x; j < n; j += 256) {
    int bk = ordb[j];
    pairs[bk * BCAP + gbase[bk] + (j - lofs[bk])] = ordv[j];
  }
}

// build_k: per-bucket degree hist + scan -> deg/rowptr; eidx at b*BCAP span.
__global__ __launch_bounds__(256) void build_k(const unsigned int* __restrict__ pairs,
                                               const int* __restrict__ bucketCount,
                                               int* __restrict__ deg,
                                               int* __restrict__ rowptr,
                                               ushort* __restrict__ eidx, int N) {
  __shared__ int h[BNODE];
  __shared__ int lofs[BNODE];
  __shared__ int cur[BNODE];
  const int b = blockIdx.x;
  const int base = b * BCAP;
  const int cnt = bucketCount[b];
  const int nodebase = b * BNODE;
  const int nloc = min(BNODE, N - nodebase);
  if (threadIdx.x < BNODE) h[threadIdx.x] = 0;
  __syncthreads();
  for (int i = threadIdx.x; i < cnt; i += 256) atomicAdd(&h[pairs[base + i] & 255u], 1);
  __syncthreads();
  if (threadIdx.x < BNODE) lofs[threadIdx.x] = h[threadIdx.x];
  __syncthreads();
  for (int off = 1; off < BNODE; off <<= 1) {
    int t = (threadIdx.x >= off && threadIdx.x < BNODE) ? lofs[threadIdx.x - off] : 0;
    __syncthreads();
    if (threadIdx.x < BNODE) lofs[threadIdx.x] += t;
    __syncthreads();
  }
  if (threadIdx.x < BNODE) {
    int ex = lofs[threadIdx.x] - h[threadIdx.x];
    cur[threadIdx.x] = ex;
    if (threadIdx.x < nloc) {
      deg[nodebase + threadIdx.x] = h[threadIdx.x];
      rowptr[nodebase + threadIdx.x] = base + ex;
    }
  }
  __syncthreads();
  for (int i = threadIdx.x; i < cnt; i += 256) {
    unsigned int v = pairs[base + i];
    int pos = atomicAdd(&cur[v & 255u], 1);
    eidx[base + pos] = (ushort)(v >> 8);
  }
}

// ---------------- column-per-lane fp8 gather mean aggregation -> bf16 --------
// One wave per node. Lane L owns output columns 2L,2L+1. Edge loop is
// wave-uniform (scalar eidx via readfirstlane'd start/deg); per edge each
// lane loads 2 B of the neighbor row (coalesced 128 B across the wave),
// 1 cvt_pk decode, 2 adds. No shfl fold, no masks, no divergence.
// 4 accumulator pairs (unroll 4) break the add dependence chain.
__global__ __launch_bounds__(256) void agg_c(const unsigned char* __restrict__ Fq,
                                             ushort* __restrict__ Ag,
                                             const ushort* __restrict__ eidx,
                                             const int* __restrict__ rowptr,
                                             const int* __restrict__ deg, int N) {
  const int lane = threadIdx.x & 63;
  const int n = blockIdx.x * 4 + (threadIdx.x >> 6);
  if (n >= N) return;
  const int start = __builtin_amdgcn_readfirstlane(rowptr[n]);
  const int d = __builtin_amdgcn_readfirstlane(deg[n]);
  const unsigned int co = (unsigned int)(lane << 1);  // byte offset of col 2L
  const ushort* ep = eidx + start;

  float a0 = 0.f, a1 = 0.f, b0 = 0.f, b1 = 0.f;
  float c0 = 0.f, c1 = 0.f, d0 = 0.f, d1 = 0.f;
  int j = 0;
  for (; j + 4 <= d; j += 4) {
    int s0 = ep[j], s1 = ep[j + 1], s2 = ep[j + 2], s3 = ep[j + 3];
    unsigned int w0 = *(const ushort*)(Fq + (size_t)s0 * HDIM + co);
    unsigned int w1 = *(const ushort*)(Fq + (size_t)s1 * HDIM + co);
    unsigned int w2 = *(const ushort*)(Fq + (size_t)s2 * HDIM + co);
    unsigned int w3 = *(const ushort*)(Fq + (size_t)s3 * HDIM + co);
    fp8x2_acc(a0, a1, w0);
    fp8x2_acc(b0, b1, w1);
    fp8x2_acc(c0, c1, w2);
    fp8x2_acc(d0, d1, w3);
  }
  for (; j < d; ++j) {
    int s0 = ep[j];
    unsigned int w0 = *(const ushort*)(Fq + (size_t)s0 * HDIM + co);
    fp8x2_acc(a0, a1, w0);
  }
  a0 += b0; a1 += b1;
  c0 += d0; c1 += d1;
  a0 += c0; a1 += c1;
  const float rd = 1.0f / fmaxf((float)d, 1.0f);
  *(unsigned int*)&Ag[(size_t)n * HDIM + (lane << 1)] = pack2(a0 * rd, a1 * rd);
}

// ---------------- bf16 MFMA GEMM, K=256 from two compact N x 128 buffers ------
// MODE 1: hb = dropout(relu(.+bias)) -> bf16 Hb + fp8 Hq. MODE 2: fout f32.
template <int MODE>
__global__ __launch_bounds__(256) void gemm_mfma(const ushort* __restrict__ Agg,
                                                 const ushort* __restrict__ F,
                                                 const ushort* __restrict__ Wc,
                                                 ushort* __restrict__ hb,
                                                 unsigned char* __restrict__ hq,
                                                 float* __restrict__ fout,
                                                 const float* __restrict__ bias,
                                                 int N) {
  __shared__ char smem[34816];            // Wl 128*136*2 = 34816; Tl 33792
  ushort* Wl = (ushort*)smem;
  float* Tl = (float*)smem;
  const int tid = threadIdx.x;
  const int lane = tid & 63;
  const int wid = tid >> 6;
  const int quad = lane >> 4;
  const int l15 = lane & 15;
  const int n0 = blockIdx.x * 64;

  int rowA = n0 + wid * 16 + l15;
  if (rowA >= N) rowA = N - 1;
  bshort8 afA[4], afF[4];
#pragma unroll
  for (int ks = 0; ks < 4; ++ks) {
    afA[ks] = *(const bshort8*)&Agg[(size_t)rowA * HDIM + ks * 32 + quad * 8];
    afF[ks] = *(const bshort8*)&F[(size_t)rowA * HDIM + ks * 32 + quad * 8];
  }

  f32x4 acc[8];
#pragma unroll
  for (int i = 0; i < 8; ++i) acc[i] = (f32x4){0.f, 0.f, 0.f, 0.f};

#pragma unroll
  for (int half = 0; half < 2; ++half) {
    __syncthreads();
#pragma unroll
    for (int i = 0; i < 8; ++i) {
      int q = i * 256 + tid;
      int row = q >> 4, seg = q & 15;
      *(uint4*)&Wl[row * 136 + seg * 8] = *(const uint4*)&Wc[row * KDIM + half * HDIM + seg * 8];
    }
    __syncthreads();
#pragma unroll
    for (int ks = 0; ks < 4; ++ks) {
#pragma unroll
      for (int os = 0; os < 8; ++os) {
        bshort8 bf = *(const bshort8*)&Wl[(os * 16 + l15) * 136 + ks * 32 + quad * 8];
        acc[os] = __builtin_amdgcn_mfma_f32_16x16x32_bf16(
            half == 0 ? afA[ks] : afF[ks], bf, acc[os], 0, 0, 0);
      }
    }
  }

  __syncthreads();  // done with Wl; reuse as transpose buffer

  const int wbase = wid * (16 * 132);
#pragma unroll
  for (int os = 0; os < 8; ++os)
#pragma unroll
    for (int r = 0; r < 4; ++r)
      Tl[wbase + (quad * 4 + r) * 132 + os * 16 + l15] = acc[os][r];

  __syncthreads();

#pragma unroll
  for (int i = 0; i < 8; ++i) {
    int q = i * 64 + lane;
    int r = q >> 5;
    int c4 = q & 31;
    int n = n0 + wid * 16 + r;
    if (n >= N) continue;
    int c = c4 * 4;
    float4 v = *(float4*)&Tl[wbase + r * 132 + c];
    const float4 bv = *(const float4*)&bias[c];
    v.x += bv.x; v.y += bv.y; v.z += bv.z; v.w += bv.w;
    if (MODE == 1) {
      v.x = v.x > 0.0f ? v.x : 0.0f;
      v.y = v.y > 0.0f ? v.y : 0.0f;
      v.z = v.z > 0.0f ? v.z : 0.0f;
      v.w = v.w > 0.0f ? v.w : 0.0f;
      unsigned int fj = (unsigned int)n * HDIM + (unsigned int)c;
      v.x = dropout_keep(fj + 0u) ? v.x * 2.0f : 0.0f;
      v.y = dropout_keep(fj + 1u) ? v.y * 2.0f : 0.0f;
      v.z = dropout_keep(fj + 2u) ? v.z * 2.0f : 0.0f;
      v.w = dropout_keep(fj + 3u) ? v.w * 2.0f : 0.0f;
      uint2 p;
      p.x = pack2(v.x, v.y);
      p.y = pack2(v.z, v.w);
      *(uint2*)&hb[(size_t)n * HDIM + c] = p;
      *(unsigned int*)&hq[(size_t)n * HDIM + c] = fp8x4_enc(v.x, v.y, v.z, v.w);
    } else {
      *(float4*)&fout[(size_t)n * HDIM + c] = v;
    }
  }
}

extern "C" void kernel_launch(void* const* d_in, const int* in_sizes, int n_in,
                              void* d_out, int out_size, void* d_ws, size_t ws_size,
                              hipStream_t stream) {
  const float* x   = (const float*)d_in[0];
  const int*   ei  = (const int*)d_in[1];
  const float* Wl0 = (const float*)d_in[2];
  const float* bl0 = (const float*)d_in[3];
  const float* Wr0 = (const float*)d_in[4];
  const float* Wl1 = (const float*)d_in[5];
  const float* bl1 = (const float*)d_in[6];
  const float* Wr1 = (const float*)d_in[7];
  float* out = (float*)d_out;

  const int N = in_sizes[0] / HDIM;  // 50000
  const int E = in_sizes[1] / 2;     // 800000
  const int* src = ei;
  const int* dst = ei + E;

  // workspace: bucketCount | deg | rowptr | pairs | eidx | Wc0 | Wc1 |
  //            Xb | Hb | Ag (bf16) | Xq | Hq (fp8)
  const int Na = (N + 63) & ~63;
  int* bucketCount = (int*)d_ws;
  int* deg         = bucketCount + NBUK;
  int* rowptr      = deg + Na;
  unsigned int* pairs = (unsigned int*)(rowptr + Na);
  ushort* eidx     = (ushort*)(pairs + NBUK * BCAP);
  size_t off = (((size_t)(eidx + NBUK * BCAP) - (size_t)d_ws) + 255) & ~(size_t)255;
  ushort* Wc0 = (ushort*)((char*)d_ws + off);          // 128*256
  ushort* Wc1 = Wc0 + 128 * KDIM;
  ushort* Xb  = Wc1 + 128 * KDIM;                      // N*128 bf16
  ushort* Hb  = Xb + (size_t)N * HDIM;                 // N*128 bf16
  ushort* Ag  = Hb + (size_t)N * HDIM;                 // N*128 bf16
  unsigned char* Xq = (unsigned char*)(Ag + (size_t)N * HDIM);  // N*128 fp8
  unsigned char* Hq = Xq + (size_t)N * HDIM;                    // N*128 fp8

  hipMemsetAsync(bucketCount, 0, NBUK * sizeof(int), stream);

  const int EB = (E + BCH - 1) / BCH;            // 391
  const int GB = (N + 63) / 64;                  // 782
  const int AB = (N + 3) / 4;                    // 12500
  const int CB = EB + 64 + (N * 32 + 255) / 256; // bin + weights + x-cvt

  bin_cvt_k<<<CB, 256, 0, stream>>>(src, dst, bucketCount, pairs, E, EB,
                                    x, Wl0, Wr0, Wl1, Wr1, Xb, Xq, Wc0, Wc1, N);
  build_k<<<NBUK, 256, 0, stream>>>(pairs, bucketCount, deg, rowptr, eidx, N);

  // layer 1
  agg_c<<<AB, 256, 0, stream>>>(Xq, Ag, eidx, rowptr, deg, N);
  gemm_mfma<1><<<GB, 256, 0, stream>>>(Ag, Xb, Wc0, Hb, Hq, nullptr, bl0, N);
  // layer 2
  agg_c<<<AB, 256, 0, stream>>>(Hq, Ag, eidx, rowptr, deg, N);
  gemm_mfma<2><<<GB, 256, 0, stream>>>(Ag, Hb, Wc1, nullptr, nullptr, out, bl1, N);
}

// Round 9
// 210.152 us; speedup vs baseline: 3.3096x; 1.0380x over previous
//
#include <hip/hip_runtime.h>
#include <hip/hip_bf16.h>

// Round 19: EXACT R10 baseline (proven passing 3x: 207.9/210.6/216.5us) with
// ONE minimal change: dropout_keep is __noinline__. The MODE1 epilogue
// previously inlined threefry x32 -> ~30KB straight-line code per wave ->
// cold-icache instruction streaming; budget algebra (R0-R6) puts gemm<1> at
// ~31us vs ~8us structural floor. One out-of-line threefry (~1KB) + 32 calls
// keeps the body icache-resident. (R18 tried the same via a loop pragma but
// the container failed twice - near-baseline code, so infra flake suspected;
// this round re-tests with the safest possible formulation.)
//   bin_cvt_k: blocks [0,EB) bucket edges; [EB,EB+64) weights->bf16;
//              rest: x -> bf16 (Xb) + fp8 (Xq).
//   build_k:   per-bucket CSR (deg/rowptr/eidx u16), proven R7-R10.
//   agg_q:     gather fp8 rows (128 B bursts), f32 accumulate, bf16 out.
//              (random-line-BW bound ~38us: R12/R16 instruction-mix invariance)
//   gemm_mfma: K=256 bf16 16x16x32 MFMA; MODE1 -> Hb + Hq; MODE2 -> f32 out.
// Dropout: JAX partitionable threefry (verified R2). absmax budget ~0.08.

#define HDIM 128
#define KDIM 256
#define NBUK 256
#define BNODE 196   // nodes per bucket (256*196 = 50176 >= 50000)
#define BCAP 4096   // edge capacity per bucket (mean 3136, sigma ~56)
#define BCH 2048    // edges per WG in bin

typedef __attribute__((ext_vector_type(8))) short bshort8;
typedef __attribute__((ext_vector_type(4))) float f32x4;
typedef __attribute__((ext_vector_type(2))) float f32x2;

__device__ __forceinline__ ushort f2b(float f) {
  __hip_bfloat16 h = __float2bfloat16(f);  // RTNE
  return *(ushort*)&h;
}
__device__ __forceinline__ unsigned int pack2(float lo, float hi) {
  return (unsigned int)f2b(lo) | ((unsigned int)f2b(hi) << 16);
}

// ---------------- fp8 e4m3 codec (HW builtins if present, manual fallback) ----
#if __has_builtin(__builtin_amdgcn_cvt_pk_f32_fp8) && __has_builtin(__builtin_amdgcn_cvt_pk_fp8_f32)
#define FP8_HW 1
#endif

__device__ __forceinline__ unsigned int fp8e1(float f) {  // manual e4m3fn RTNE
  unsigned int u = __float_as_uint(f);
  unsigned int s = (u >> 24) & 0x80u;
  unsigned int mag = u & 0x7FFFFFFFu;
  if (mag < 0x38800000u) return s;           // flush |f|<2^-6 to zero
  if (mag > 0x43E00000u) mag = 0x43E00000u;  // clamp to 448
  unsigned int r = mag + 0x7FFFFu + ((mag >> 20) & 1u);
  return s | ((r >> 20) - 960u);
}
__device__ __forceinline__ float fp8d1(unsigned int b) {
  unsigned int v = b & 0x7Fu;
  float fn = __uint_as_float(((b & 0x80u) << 24) | ((v + 960u) << 20));
  return v >= 8u ? fn : 0.0f;  // encoder flushes; only v==0 occurs below 8
}

__device__ __forceinline__ unsigned int fp8x4_enc(float f0, float f1, float f2, float f3) {
#ifdef FP8_HW
  int u = 0;
  u = __builtin_amdgcn_cvt_pk_fp8_f32(f0, f1, u, false);
  u = __builtin_amdgcn_cvt_pk_fp8_f32(f2, f3, u, true);
  return (unsigned int)u;
#else
  return fp8e1(f0) | (fp8e1(f1) << 8) | (fp8e1(f2) << 16) | (fp8e1(f3) << 24);
#endif
}
__device__ __forceinline__ void fp8x4_acc(float* a, unsigned int w) {
#ifdef FP8_HW
  f32x2 lo = __builtin_amdgcn_cvt_pk_f32_fp8((int)w, false);
  f32x2 hi = __builtin_amdgcn_cvt_pk_f32_fp8((int)w, true);
  a[0] += lo.x; a[1] += lo.y; a[2] += hi.x; a[3] += hi.y;
#else
  a[0] += fp8d1(w & 255u); a[1] += fp8d1((w >> 8) & 255u);
  a[2] += fp8d1((w >> 16) & 255u); a[3] += fp8d1(w >> 24);
#endif
}

// ---------------- Threefry-2x32 (JAX partitionable mode, verified R2) --------
__device__ __forceinline__ unsigned int tf_rotl(unsigned int x, int d) {
  return (x << d) | (x >> (32 - d));
}
// OUT-OF-LINE: one ~1KB copy instead of 32 inlined copies (~30KB) in the
// MODE1 epilogue -> body stays icache-resident.
__device__ __noinline__ bool dropout_keep(unsigned int j) {
  unsigned int x0 = 0u, x1 = j;
  const unsigned int ks0 = 0u, ks1 = 42u, ks2 = 0x1BD11BDAu ^ 0u ^ 42u;
  x0 += ks0; x1 += ks1;
#define TF_R(r) { x0 += x1; x1 = tf_rotl(x1, (r)); x1 ^= x0; }
  TF_R(13) TF_R(15) TF_R(26) TF_R(6)
  x0 += ks1; x1 += ks2 + 1u;
  TF_R(17) TF_R(29) TF_R(16) TF_R(24)
  x0 += ks2; x1 += ks0 + 2u;
  TF_R(13) TF_R(15) TF_R(26) TF_R(6)
  x0 += ks0; x1 += ks1 + 3u;
  TF_R(17) TF_R(29) TF_R(16) TF_R(24)
  x0 += ks1; x1 += ks2 + 4u;
  TF_R(13) TF_R(15) TF_R(26) TF_R(6)
  x0 += ks2; x1 += ks0 + 5u;
#undef TF_R
  unsigned int r = x0 ^ x1;
  float u = __uint_as_float((r >> 9) | 0x3f800000u) - 1.0f;
  return u < 0.5f;
}

// ---------------- bin (bucket edges) + cvt (weights, x) merged ----------------
__global__ __launch_bounds__(256) void bin_cvt_k(
    const int* __restrict__ src, const int* __restrict__ dst,
    int* __restrict__ bucketCount, unsigned int* __restrict__ pairs, int E, int EB,
    const float* __restrict__ x,
    const float* __restrict__ Wl0, const float* __restrict__ Wr0,
    const float* __restrict__ Wl1, const float* __restrict__ Wr1,
    ushort* __restrict__ Xb, unsigned char* __restrict__ Xq,
    ushort* __restrict__ Wc0, ushort* __restrict__ Wc1, int N) {
  __shared__ int hist[NBUK];
  __shared__ int lofs[NBUK];
  __shared__ int lcur[NBUK];
  __shared__ int gbase[NBUK];
  __shared__ unsigned int ordv[BCH];
  __shared__ unsigned char ordb[BCH];

  int b = blockIdx.x;
  if (b >= EB) {
    b -= EB;
    if (b < 64) {  // weights -> combined bf16 [Wl | Wr] rows of 256
      int t = b * 256 + threadIdx.x;  // 16384
      int o = t >> 7, k = t & 127;
      Wc0[o * KDIM + k] = f2b(Wl0[t]);
      Wc0[o * KDIM + HDIM + k] = f2b(Wr0[t]);
      Wc1[o * KDIM + k] = f2b(Wl1[t]);
      Wc1[o * KDIM + HDIM + k] = f2b(Wr1[t]);
    } else {       // x -> bf16 + fp8
      int t = (b - 64) * 256 + threadIdx.x;
      if (t < N * 32) {
        int n = t >> 5, c4 = t & 31;
        float4 v = *(const float4*)&x[(size_t)n * HDIM + c4 * 4];
        uint2 p;
        p.x = pack2(v.x, v.y);
        p.y = pack2(v.z, v.w);
        *(uint2*)&Xb[(size_t)n * HDIM + c4 * 4] = p;
        *(unsigned int*)&Xq[(size_t)n * HDIM + c4 * 4] = fp8x4_enc(v.x, v.y, v.z, v.w);
      }
    }
    return;
  }

  // ---- bin work ----
  hist[threadIdx.x] = 0;
  __syncthreads();
  int begin = b * BCH;
  int n = min(BCH, E - begin);
  unsigned int vals[BCH / 256];
  int bks[BCH / 256];
  int cnt = 0;
  for (int i = threadIdx.x; i < n; i += 256) {
    int s = src[begin + i], d = dst[begin + i];
    int bk = d / BNODE;
    int dloc = d - bk * BNODE;
    vals[cnt] = ((unsigned int)s << 8) | (unsigned int)dloc;
    bks[cnt] = bk;
    ++cnt;
    atomicAdd(&hist[bk], 1);
  }
  __syncthreads();
  {
    int v = hist[threadIdx.x];
    lofs[threadIdx.x] = v;
    __syncthreads();
    for (int off = 1; off < NBUK; off <<= 1) {
      int t = (threadIdx.x >= off) ? lofs[threadIdx.x - off] : 0;
      __syncthreads();
      lofs[threadIdx.x] += t;
      __syncthreads();
    }
    int ex = lofs[threadIdx.x] - v;
    __syncthreads();
    lofs[threadIdx.x] = ex;
    lcur[threadIdx.x] = ex;
    gbase[threadIdx.x] = atomicAdd(&bucketCount[threadIdx.x], v);
  }
  __syncthreads();
  for (int k = 0; k < cnt; ++k) {
    int bk = bks[k];
    int p = atomicAdd(&lcur[bk], 1);
    ordv[p] = vals[k];
    ordb[p] = (unsigned char)bk;
  }
  __syncthreads();
  for (int j = threadIdx.x; j < n; j += 256) {
    int bk = ordb[j];
    pairs[bk * BCAP + gbase[bk] + (j - lofs[bk])] = ordv[j];
  }
}

// build_k: per-bucket degree hist + scan -> deg/rowptr; eidx at b*BCAP span.
__global__ __launch_bounds__(256) void build_k(const unsigned int* __restrict__ pairs,
                                               const int* __restrict__ bucketCount,
                                               int* __restrict__ deg,
                                               int* __restrict__ rowptr,
                                               ushort* __restrict__ eidx, int N) {
  __shared__ int h[BNODE];
  __shared__ int lofs[BNODE];
  __shared__ int cur[BNODE];
  const int b = blockIdx.x;
  const int base = b * BCAP;
  const int cnt = bucketCount[b];
  const int nodebase = b * BNODE;
  const int nloc = min(BNODE, N - nodebase);
  if (threadIdx.x < BNODE) h[threadIdx.x] = 0;
  __syncthreads();
  for (int i = threadIdx.x; i < cnt; i += 256) atomicAdd(&h[pairs[base + i] & 255u], 1);
  __syncthreads();
  if (threadIdx.x < BNODE) lofs[threadIdx.x] = h[threadIdx.x];
  __syncthreads();
  for (int off = 1; off < BNODE; off <<= 1) {
    int t = (threadIdx.x >= off && threadIdx.x < BNODE) ? lofs[threadIdx.x - off] : 0;
    __syncthreads();
    if (threadIdx.x < BNODE) lofs[threadIdx.x] += t;
    __syncthreads();
  }
  if (threadIdx.x < BNODE) {
    int ex = lofs[threadIdx.x] - h[threadIdx.x];
    cur[threadIdx.x] = ex;
    if (threadIdx.x < nloc) {
      deg[nodebase + threadIdx.x] = h[threadIdx.x];
      rowptr[nodebase + threadIdx.x] = base + ex;
    }
  }
  __syncthreads();
  for (int i = threadIdx.x; i < cnt; i += 256) {
    unsigned int v = pairs[base + i];
    int pos = atomicAdd(&cur[v & 255u], 1);
    eidx[base + pos] = (ushort)(v >> 8);
  }
}

// ---------------- fp8 gather mean aggregation -> bf16 ----------------
// One wave per node. es = lane>>3 (edge subgroup 0..7), cl = lane&7 (16 B of
// the 128 B fp8 row). unroll 2 -> 16 edges in flight per wave (full rows).
__global__ __launch_bounds__(256) void agg_q(const unsigned char* __restrict__ Fq,
                                             ushort* __restrict__ Ag,
                                             const ushort* __restrict__ eidx,
                                             const int* __restrict__ rowptr,
                                             const int* __restrict__ deg, int N) {
  const int lane = threadIdx.x & 63;
  const int n = blockIdx.x * 4 + (threadIdx.x >> 6);
  if (n >= N) return;
  const int start = rowptr[n];
  const int d = deg[n];
  const int es = lane >> 3;
  const int cl = lane & 7;
  float a[16];
#pragma unroll
  for (int i = 0; i < 16; ++i) a[i] = 0.0f;
  for (int j = 0; j < d; j += 16) {
    uint4 v[2];
    bool m[2];
#pragma unroll
    for (int u = 0; u < 2; ++u) {
      int e = j + u * 8 + es;
      m[u] = e < d;
      if (m[u]) {
        int s = eidx[start + e];
        v[u] = *(const uint4*)&Fq[(size_t)s * HDIM + cl * 16];
      }
    }
#pragma unroll
    for (int u = 0; u < 2; ++u)
      if (m[u]) {
        fp8x4_acc(&a[0], v[u].x);
        fp8x4_acc(&a[4], v[u].y);
        fp8x4_acc(&a[8], v[u].z);
        fp8x4_acc(&a[12], v[u].w);
      }
  }
  // fold the 8 edge subgroups (lane bits 3,4,5)
#pragma unroll
  for (int i = 0; i < 16; ++i) {
    a[i] += __shfl_xor(a[i], 8, 64);
    a[i] += __shfl_xor(a[i], 16, 64);
    a[i] += __shfl_xor(a[i], 32, 64);
  }
  if (es == 0) {
    float rd = 1.0f / fmaxf((float)d, 1.0f);
    uint4 p0, p1;
    p0.x = pack2(a[0] * rd, a[1] * rd);
    p0.y = pack2(a[2] * rd, a[3] * rd);
    p0.z = pack2(a[4] * rd, a[5] * rd);
    p0.w = pack2(a[6] * rd, a[7] * rd);
    p1.x = pack2(a[8] * rd, a[9] * rd);
    p1.y = pack2(a[10] * rd, a[11] * rd);
    p1.z = pack2(a[12] * rd, a[13] * rd);
    p1.w = pack2(a[14] * rd, a[15] * rd);
    *(uint4*)&Ag[(size_t)n * HDIM + cl * 16] = p0;
    *(uint4*)&Ag[(size_t)n * HDIM + cl * 16 + 8] = p1;
  }
}

// ---------------- bf16 MFMA GEMM, K=256 from two compact N x 128 buffers ------
// MODE 1: hb = dropout(relu(.+bias)) -> bf16 Hb + fp8 Hq. MODE 2: fout f32.
template <int MODE>
__global__ __launch_bounds__(256) void gemm_mfma(const ushort* __restrict__ Agg,
                                                 const ushort* __restrict__ F,
                                                 const ushort* __restrict__ Wc,
                                                 ushort* __restrict__ hb,
                                                 unsigned char* __restrict__ hq,
                                                 float* __restrict__ fout,
                                                 const float* __restrict__ bias,
                                                 int N) {
  __shared__ char smem[34816];            // Wl 128*136*2 = 34816; Tl 33792
  ushort* Wl = (ushort*)smem;
  float* Tl = (float*)smem;
  const int tid = threadIdx.x;
  const int lane = tid & 63;
  const int wid = tid >> 6;
  const int quad = lane >> 4;
  const int l15 = lane & 15;
  const int n0 = blockIdx.x * 64;

  int rowA = n0 + wid * 16 + l15;
  if (rowA >= N) rowA = N - 1;
  bshort8 afA[4], afF[4];
#pragma unroll
  for (int ks = 0; ks < 4; ++ks) {
    afA[ks] = *(const bshort8*)&Agg[(size_t)rowA * HDIM + ks * 32 + quad * 8];
    afF[ks] = *(const bshort8*)&F[(size_t)rowA * HDIM + ks * 32 + quad * 8];
  }

  f32x4 acc[8];
#pragma unroll
  for (int i = 0; i < 8; ++i) acc[i] = (f32x4){0.f, 0.f, 0.f, 0.f};

#pragma unroll
  for (int half = 0; half < 2; ++half) {
    __syncthreads();
#pragma unroll
    for (int i = 0; i < 8; ++i) {
      int q = i * 256 + tid;
      int row = q >> 4, seg = q & 15;
      *(uint4*)&Wl[row * 136 + seg * 8] = *(const uint4*)&Wc[row * KDIM + half * HDIM + seg * 8];
    }
    __syncthreads();
#pragma unroll
    for (int ks = 0; ks < 4; ++ks) {
#pragma unroll
      for (int os = 0; os < 8; ++os) {
        bshort8 bf = *(const bshort8*)&Wl[(os * 16 + l15) * 136 + ks * 32 + quad * 8];
        acc[os] = __builtin_amdgcn_mfma_f32_16x16x32_bf16(
            half == 0 ? afA[ks] : afF[ks], bf, acc[os], 0, 0, 0);
      }
    }
  }

  __syncthreads();  // done with Wl; reuse as transpose buffer

  const int wbase = wid * (16 * 132);
#pragma unroll
  for (int os = 0; os < 8; ++os)
#pragma unroll
    for (int r = 0; r < 4; ++r)
      Tl[wbase + (quad * 4 + r) * 132 + os * 16 + l15] = acc[os][r];

  __syncthreads();

#pragma unroll
  for (int i = 0; i < 8; ++i) {
    int q = i * 64 + lane;
    int r = q >> 5;
    int c4 = q & 31;
    int n = n0 + wid * 16 + r;
    if (n >= N) continue;
    int c = c4 * 4;
    float4 v = *(float4*)&Tl[wbase + r * 132 + c];
    const float4 bv = *(const float4*)&bias[c];
    v.x += bv.x; v.y += bv.y; v.z += bv.z; v.w += bv.w;
    if (MODE == 1) {
      v.x = v.x > 0.0f ? v.x : 0.0f;
      v.y = v.y > 0.0f ? v.y : 0.0f;
      v.z = v.z > 0.0f ? v.z : 0.0f;
      v.w = v.w > 0.0f ? v.w : 0.0f;
      unsigned int fj = (unsigned int)n * HDIM + (unsigned int)c;
      v.x = dropout_keep(fj + 0u) ? v.x * 2.0f : 0.0f;
      v.y = dropout_keep(fj + 1u) ? v.y * 2.0f : 0.0f;
      v.z = dropout_keep(fj + 2u) ? v.z * 2.0f : 0.0f;
      v.w = dropout_keep(fj + 3u) ? v.w * 2.0f : 0.0f;
      uint2 p;
      p.x = pack2(v.x, v.y);
      p.y = pack2(v.z, v.w);
      *(uint2*)&hb[(size_t)n * HDIM + c] = p;
      *(unsigned int*)&hq[(size_t)n * HDIM + c] = fp8x4_enc(v.x, v.y, v.z, v.w);
    } else {
      *(float4*)&fout[(size_t)n * HDIM + c] = v;
    }
  }
}

extern "C" void kernel_launch(void* const* d_in, const int* in_sizes, int n_in,
                              void* d_out, int out_size, void* d_ws, size_t ws_size,
                              hipStream_t stream) {
  const float* x   = (const float*)d_in[0];
  const int*   ei  = (const int*)d_in[1];
  const float* Wl0 = (const float*)d_in[2];
  const float* bl0 = (const float*)d_in[3];
  const float* Wr0 = (const float*)d_in[4];
  const float* Wl1 = (const float*)d_in[5];
  const float* bl1 = (const float*)d_in[6];
  const float* Wr1 = (const float*)d_in[7];
  float* out = (float*)d_out;

  const int N = in_sizes[0] / HDIM;  // 50000
  const int E = in_sizes[1] / 2;     // 800000
  const int* src = ei;
  const int* dst = ei + E;

  // workspace: bucketCount | deg | rowptr | pairs | eidx | Wc0 | Wc1 |
  //            Xb | Hb | Ag (bf16) | Xq | Hq (fp8)
  const int Na = (N + 63) & ~63;
  int* bucketCount = (int*)d_ws;
  int* deg         = bucketCount + NBUK;
  int* rowptr      = deg + Na;
  unsigned int* pairs = (unsigned int*)(rowptr + Na);
  ushort* eidx     = (ushort*)(pairs + NBUK * BCAP);
  size_t off = (((size_t)(eidx + NBUK * BCAP) - (size_t)d_ws) + 255) & ~(size_t)255;
  ushort* Wc0 = (ushort*)((char*)d_ws + off);          // 128*256
  ushort* Wc1 = Wc0 + 128 * KDIM;
  ushort* Xb  = Wc1 + 128 * KDIM;                      // N*128 bf16
  ushort* Hb  = Xb + (size_t)N * HDIM;                 // N*128 bf16
  ushort* Ag  = Hb + (size_t)N * HDIM;                 // N*128 bf16
  unsigned char* Xq = (unsigned char*)(Ag + (size_t)N * HDIM);  // N*128 fp8
  unsigned char* Hq = Xq + (size_t)N * HDIM;                    // N*128 fp8

  hipMemsetAsync(bucketCount, 0, NBUK * sizeof(int), stream);

  const int EB = (E + BCH - 1) / BCH;            // 391
  const int GB = (N + 63) / 64;                  // 782
  const int AB = (N + 3) / 4;                    // 12500
  const int CB = EB + 64 + (N * 32 + 255) / 256; // bin + weights + x-cvt

  bin_cvt_k<<<CB, 256, 0, stream>>>(src, dst, bucketCount, pairs, E, EB,
                                    x, Wl0, Wr0, Wl1, Wr1, Xb, Xq, Wc0, Wc1, N);
  build_k<<<NBUK, 256, 0, stream>>>(pairs, bucketCount, deg, rowptr, eidx, N);

  // layer 1
  agg_q<<<AB, 256, 0, stream>>>(Xq, Ag, eidx, rowptr, deg, N);
  gemm_mfma<1><<<GB, 256, 0, stream>>>(Ag, Xb, Wc0, Hb, Hq, nullptr, bl0, N);
  // layer 2
  agg_q<<<AB, 256, 0, stream>>>(Hq, Ag, eidx, rowptr, deg, N);
  gemm_mfma<2><<<GB, 256, 0, stream>>>(Ag, Hb, Wc1, nullptr, nullptr, out, bl1, N);
}